// Round 10
// baseline (72.152 us; speedup 1.0000x reference)
//
#include <hip/hip_runtime.h>
#include <hip/hip_bf16.h>
#include <math.h>

// Problem constants
#define BS 8
#define NQ 4096
#define E  256
#define NH 8
#define NP 4
#define HD 32
#define GW 64
#define GH 64
#define T  (BS * NQ)     // 32768
#define NPAD 384
#define MSTR 96          // meta row: 64 offsets + 32 logits (bf16)

typedef __attribute__((ext_vector_type(8))) short bf16x8;
typedef __attribute__((ext_vector_type(4))) float f32x4;
typedef __attribute__((ext_vector_type(8))) unsigned short u16x8;

__device__ __forceinline__ float b2f(unsigned short u) {
    union { unsigned int i; float f; } x; x.i = ((unsigned int)u) << 16; return x.f;
}
__device__ __forceinline__ unsigned short f2b(float f) {
    __hip_bfloat16 h = __float2bfloat16(f);
    return *reinterpret_cast<unsigned short*>(&h);
}
__device__ __forceinline__ void gload16(const void* g, void* l) {
    __builtin_amdgcn_global_load_lds(
        (__attribute__((address_space(1))) void*)g,
        (__attribute__((address_space(3))) void*)l, 16, 0, 0);
}

// Swizzled granule layout (16B granules): stored_chunk = chunk ^ (row & 7).
// Staging lane-linear dest + permuted source = coalesced; frag ds_read_b128
// spreads 16 lanes over 8 bank-quads (2-way = free).

// ---------------------------------------------------------------------------
// prep: Wcat (NPAD x 256 bf16), Wo (256x256 bf16), bcat (fp32 NPAD)
// ---------------------------------------------------------------------------
__global__ __launch_bounds__(256) void prep_weights(
    const float* __restrict__ vw, const float* __restrict__ vb,
    const float* __restrict__ ow, const float* __restrict__ ob,
    const float* __restrict__ aw, const float* __restrict__ ab,
    const float* __restrict__ outw,
    unsigned short* __restrict__ Wcat, unsigned short* __restrict__ Wo,
    float* __restrict__ bcat)
{
    int i = blockIdx.x * 256 + threadIdx.x;
    if (i < NPAD * E) {
        int n = i >> 8, k = i & 255;
        float w = 0.f;
        if      (n < 256) w = vw[n * E + k];
        else if (n < 320) w = ow[(n - 256) * E + k];
        else if (n < 352) w = aw[(n - 320) * E + k];
        Wcat[i] = f2b(w);
    } else {
        int j = i - NPAD * E;
        if (j < E * E) Wo[j] = f2b(outw[j]);
    }
    if (i < NPAD) {
        float bv = 0.f;
        if      (i < 256) bv = vb[i];
        else if (i < 320) bv = ob[i - 256];
        else if (i < 352) bv = ab[i - 320];
        bcat[i] = bv;
    }
}

// ---------------------------------------------------------------------------
// GEMM1 (projection): 64 rows x 384 cols per block -> query read ONCE.
// BK=64, 4 K-steps. 8 waves (2m x 4n), wave tile 32x96. LDS 56KB.
// (unchanged from round 8)
// ---------------------------------------------------------------------------
__global__ __launch_bounds__(512) void gemm_proj(
    const float* __restrict__ Aq,
    const unsigned short* __restrict__ W,
    const float* __restrict__ bias,
    unsigned short* __restrict__ Vt,
    unsigned short* __restrict__ Mt)
{
    __shared__ __align__(16) unsigned short ldsA[4096];   // 512 granules
    __shared__ __align__(16) unsigned short ldsB[24576];  // 3072 granules

    const int tid  = threadIdx.x;
    const int lane = tid & 63;
    const int wave = tid >> 6;      // 0..7
    const int wm   = wave >> 2;     // 0..1 : 32-row halves
    const int wn   = wave & 3;      // 0..3 : 96-col quarters
    const int bm   = blockIdx.x * 64;
    const int lrow = lane & 15, lchunk = lane >> 4;

    f32x4 acc[2][6] = {};

    for (int k0 = 0; k0 < 256; k0 += 64) {
#pragma unroll
        for (int p = 0; p < 6; ++p) {
            int g = p * 512 + tid;
            int row = g >> 3;
            int c = (g & 7) ^ (row & 7);
            gload16(W + (size_t)row * 256 + k0 + c * 8, &ldsB[(size_t)g * 8]);
        }
        {
            int row = tid >> 3;
            int c = (tid & 7) ^ (row & 7);
            const float* ap = Aq + (size_t)(bm + row) * 256 + k0 + c * 8;
            float4 f0 = *(const float4*)(ap + 0);
            float4 f1 = *(const float4*)(ap + 4);
            u16x8 o;
            o[0]=f2b(f0.x); o[1]=f2b(f0.y); o[2]=f2b(f0.z); o[3]=f2b(f0.w);
            o[4]=f2b(f1.x); o[5]=f2b(f1.y); o[6]=f2b(f1.z); o[7]=f2b(f1.w);
            *(u16x8*)&ldsA[(size_t)tid * 8] = o;
        }
        __syncthreads();

#pragma unroll
        for (int kk = 0; kk < 2; ++kk) {
            const int C = kk * 4 + lchunk;
            bf16x8 af[2], bfr[6];
#pragma unroll
            for (int m = 0; m < 2; ++m) {
                int row = wm * 32 + m * 16 + lrow;
                af[m] = *(const bf16x8*)&ldsA[(size_t)(row * 8 + (C ^ (row & 7))) * 8];
            }
#pragma unroll
            for (int n = 0; n < 6; ++n) {
                int row = wn * 96 + n * 16 + lrow;
                bfr[n] = *(const bf16x8*)&ldsB[(size_t)(row * 8 + (C ^ (row & 7))) * 8];
            }
#pragma unroll
            for (int m = 0; m < 2; ++m)
#pragma unroll
                for (int n = 0; n < 6; ++n)
                    acc[m][n] = __builtin_amdgcn_mfma_f32_16x16x32_bf16(
                        af[m], bfr[n], acc[m][n], 0, 0, 0);
        }
        __syncthreads();
    }

    const int orow0 = (lane >> 4) * 4;
    const int ocol  = lane & 15;
#pragma unroll
    for (int n = 0; n < 6; ++n) {
        int colg = wn * 96 + n * 16 + ocol;
        if (colg >= 352) continue;
        float bv = bias[colg];
#pragma unroll
        for (int m = 0; m < 2; ++m) {
#pragma unroll
            for (int r = 0; r < 4; ++r) {
                int rowg = bm + wm * 32 + m * 16 + orow0 + r;
                unsigned short v = f2b(acc[m][n][r] + bv);
                if (colg < 256) {
                    int b = rowg >> 12, q = rowg & 4095;
                    int h = colg >> 5, ch = colg & 31;
                    Vt[((size_t)(((b << 3) + h) << 12) + q) * 32 + ch] = v;
                } else if (colg < 320) {
                    Mt[(size_t)rowg * MSTR + (colg - 256)] = v;
                } else {
                    Mt[(size_t)rowg * MSTR + 64 + (colg - 320)] = v;
                }
            }
        }
    }
}

// ---------------------------------------------------------------------------
// Sampling: ONE thread per (t,h), all 32 channels. Softmax/offsets/weights
// computed once per (t,h) (was 4x in round 8). 256K threads, 1024 blocks,
// XCD-swizzled (1024 = 8*128) so each XCD's L2 holds one 2MB batch image.
// Each corner = 4 consecutive 16B loads of one 64B line (self-coalescing).
// Branchless clamped+masked bilinear.
// ---------------------------------------------------------------------------
__global__ __launch_bounds__(256) void sample_kernel(
    const unsigned short* __restrict__ Vt,
    const unsigned short* __restrict__ Mt,
    unsigned short* __restrict__ S)
{
    const int bid = blockIdx.x;
    const int blk = ((bid & 7) << 7) + (bid >> 3);   // bijective, 1024 = 8*128
    const int gid = blk * 256 + threadIdx.x;
    const int h  = gid & 7;
    const int t  = gid >> 3;
    const int b  = t >> 12;
    const int q  = t & 4095;

    const float refx = (float)(q & 63) * (64.0f / 63.0f);
    const float refy = (float)(q >> 6) * (64.0f / 63.0f);

    const unsigned short* __restrict__ mrow = Mt + (size_t)t * MSTR;
    u16x8  offv = *(const u16x8*)&mrow[h * 8];
    ushort4 lg  = *(const ushort4*)&mrow[64 + h * 4];

    float l0 = b2f(lg.x), l1 = b2f(lg.y), l2 = b2f(lg.z), l3 = b2f(lg.w);
    float m = fmaxf(fmaxf(l0, l1), fmaxf(l2, l3));
    float e0 = __expf(l0 - m), e1 = __expf(l1 - m);
    float e2 = __expf(l2 - m), e3 = __expf(l3 - m);
    float inv = 1.0f / (e0 + e1 + e2 + e3);
    float at[4] = {e0 * inv, e1 * inv, e2 * inv, e3 * inv};

    const unsigned short* __restrict__ vbase =
        Vt + ((size_t)(((b << 3) + h) << 12)) * 32;

    float acc[32] = {};
#pragma unroll
    for (int p = 0; p < NP; ++p) {
        float ox = b2f(offv[2 * p]);
        float oy = b2f(offv[2 * p + 1]);
        float px = refx + ox - 0.5f;
        float py = refy + oy - 0.5f;
        float fx = floorf(px), fy = floorf(py);
        int x0 = (int)fx, y0 = (int)fy;
        float wx = px - fx, wy = py - fy;
        float a = at[p];

        int x1 = x0 + 1, y1 = y0 + 1;
        float vx0 = (x0 >= 0 && x0 < GW) ? 1.f : 0.f;
        float vx1 = (x1 >= 0 && x1 < GW) ? 1.f : 0.f;
        float vy0 = (y0 >= 0 && y0 < GH) ? 1.f : 0.f;
        float vy1 = (y1 >= 0 && y1 < GH) ? 1.f : 0.f;

        float w00 = (1.f - wx) * (1.f - wy) * a * vx0 * vy0;
        float w10 = wx * (1.f - wy) * a * vx1 * vy0;
        float w01 = (1.f - wx) * wy * a * vx0 * vy1;
        float w11 = wx * wy * a * vx1 * vy1;

        int x0c = min(max(x0, 0), GW - 1), x1c = min(max(x1, 0), GW - 1);
        int y0c = min(max(y0, 0), GH - 1), y1c = min(max(y1, 0), GH - 1);

#define CORNER(Y, X, WT)                                                     \
        {                                                                    \
            const unsigned short* src = vbase + (size_t)((Y) * GW + (X)) * 32;\
            u16x8 s0 = *(const u16x8*)(src + 0);                             \
            u16x8 s1 = *(const u16x8*)(src + 8);                             \
            u16x8 s2 = *(const u16x8*)(src + 16);                            \
            u16x8 s3 = *(const u16x8*)(src + 24);                            \
            _Pragma("unroll")                                                \
            for (int j = 0; j < 8; ++j) {                                    \
                acc[j]      += (WT) * b2f(s0[j]);                            \
                acc[8 + j]  += (WT) * b2f(s1[j]);                            \
                acc[16 + j] += (WT) * b2f(s2[j]);                            \
                acc[24 + j] += (WT) * b2f(s3[j]);                            \
            }                                                                \
        }
        CORNER(y0c, x0c, w00);
        CORNER(y0c, x1c, w10);
        CORNER(y1c, x0c, w01);
        CORNER(y1c, x1c, w11);
#undef CORNER
    }

    unsigned short* __restrict__ dst = S + (size_t)t * E + h * HD;
#pragma unroll
    for (int g = 0; g < 4; ++g) {
        u16x8 o;
#pragma unroll
        for (int j = 0; j < 8; ++j) o[j] = f2b(acc[g * 8 + j]);
        *(u16x8*)&dst[g * 8] = o;
    }
}

// ---------------------------------------------------------------------------
// GEMM2 (output projection): 64 rows x 256 cols per block -> S read ONCE.
// BK=64, 4 K-steps. 8 waves (2m x 4n), wave tile 32x64. LDS 40KB.
// (unchanged from round 8)
// ---------------------------------------------------------------------------
__global__ __launch_bounds__(512) void gemm_out(
    const unsigned short* __restrict__ A,
    const unsigned short* __restrict__ W,
    const float* __restrict__ bias,
    const float* __restrict__ resid,
    float* __restrict__ Out)
{
    __shared__ __align__(16) unsigned short ldsA[4096];   // 512 granules
    __shared__ __align__(16) unsigned short ldsB[16384];  // 2048 granules

    const int tid  = threadIdx.x;
    const int lane = tid & 63;
    const int wave = tid >> 6;
    const int wm   = wave >> 2;
    const int wn   = wave & 3;
    const int bm   = blockIdx.x * 64;
    const int lrow = lane & 15, lchunk = lane >> 4;

    f32x4 acc[2][4] = {};

    for (int k0 = 0; k0 < 256; k0 += 64) {
        {
            int row = tid >> 3;
            int c = (tid & 7) ^ (row & 7);
            gload16(A + (size_t)(bm + row) * 256 + k0 + c * 8,
                    &ldsA[(size_t)tid * 8]);
        }
#pragma unroll
        for (int p = 0; p < 4; ++p) {
            int g = p * 512 + tid;
            int row = g >> 3;
            int c = (g & 7) ^ (row & 7);
            gload16(W + (size_t)row * 256 + k0 + c * 8, &ldsB[(size_t)g * 8]);
        }
        __syncthreads();

#pragma unroll
        for (int kk = 0; kk < 2; ++kk) {
            const int C = kk * 4 + lchunk;
            bf16x8 af[2], bfr[4];
#pragma unroll
            for (int m = 0; m < 2; ++m) {
                int row = wm * 32 + m * 16 + lrow;
                af[m] = *(const bf16x8*)&ldsA[(size_t)(row * 8 + (C ^ (row & 7))) * 8];
            }
#pragma unroll
            for (int n = 0; n < 4; ++n) {
                int row = wn * 64 + n * 16 + lrow;
                bfr[n] = *(const bf16x8*)&ldsB[(size_t)(row * 8 + (C ^ (row & 7))) * 8];
            }
#pragma unroll
            for (int m = 0; m < 2; ++m)
#pragma unroll
                for (int n = 0; n < 4; ++n)
                    acc[m][n] = __builtin_amdgcn_mfma_f32_16x16x32_bf16(
                        af[m], bfr[n], acc[m][n], 0, 0, 0);
        }
        __syncthreads();
    }

    const int orow0 = (lane >> 4) * 4;
    const int ocol  = lane & 15;
#pragma unroll
    for (int m = 0; m < 2; ++m) {
#pragma unroll
        for (int n = 0; n < 4; ++n) {
            int colg = wn * 64 + n * 16 + ocol;
            float bv = bias[colg];
#pragma unroll
            for (int r = 0; r < 4; ++r) {
                int rowg = bm + wm * 32 + m * 16 + orow0 + r;
                Out[(size_t)rowg * 256 + colg] =
                    acc[m][n][r] + bv + 2.0f * resid[(size_t)rowg * 256 + colg];
            }
        }
    }
}

// ---------------------------------------------------------------------------
extern "C" void kernel_launch(void* const* d_in, const int* in_sizes, int n_in,
                              void* d_out, int out_size, void* d_ws, size_t ws_size,
                              hipStream_t stream)
{
    const float* query   = (const float*)d_in[0];
    const float* value_w = (const float*)d_in[1];
    const float* value_b = (const float*)d_in[2];
    const float* off_w   = (const float*)d_in[3];
    const float* off_b   = (const float*)d_in[4];
    const float* attn_w  = (const float*)d_in[5];
    const float* attn_b  = (const float*)d_in[6];
    const float* out_w   = (const float*)d_in[7];
    const float* out_b   = (const float*)d_in[8];

    char* w = (char*)d_ws;
    unsigned short* Vt   = (unsigned short*)w;  w += (size_t)T * E * 2;      // 16 MB
    unsigned short* Mt   = (unsigned short*)w;  w += (size_t)T * MSTR * 2;   // 6 MB
    unsigned short* S    = (unsigned short*)w;  w += (size_t)T * E * 2;      // 16 MB
    unsigned short* Wcat = (unsigned short*)w;  w += (size_t)NPAD * E * 2;
    unsigned short* Wo   = (unsigned short*)w;  w += (size_t)E * E * 2;
    float*          bcat = (float*)w;

    prep_weights<<<(NPAD * E + E * E + 255) / 256, 256, 0, stream>>>(
        value_w, value_b, off_w, off_b, attn_w, attn_b, out_w, Wcat, Wo, bcat);

    gemm_proj<<<T / 64, 512, 0, stream>>>(query, Wcat, bcat, Vt, Mt);

    sample_kernel<<<T * 8 / 256, 256, 0, stream>>>(Vt, Mt, S);

    gemm_out<<<T / 64, 512, 0, stream>>>(S, Wo, out_b, query, (float*)d_out);
}

// Round 11
// 55.733 us; speedup vs baseline: 1.2946x; 1.2946x over previous
//
#include <hip/hip_runtime.h>
#include <hip/hip_bf16.h>
#include <math.h>

// Problem constants
#define BS 8
#define NQ 4096
#define E  256
#define NH 8
#define NP 4
#define HD 32
#define GW 64
#define GH 64
#define T  (BS * NQ)     // 32768
#define NPAD 384
#define MSTR 128         // meta row: per-head 16 shorts = 8 off + 4 logits + 4 pad

typedef __attribute__((ext_vector_type(8))) short bf16x8;
typedef __attribute__((ext_vector_type(4))) float f32x4;
typedef __attribute__((ext_vector_type(8))) unsigned short u16x8;

__device__ __forceinline__ float b2f(unsigned short u) {
    union { unsigned int i; float f; } x; x.i = ((unsigned int)u) << 16; return x.f;
}
__device__ __forceinline__ unsigned short f2b(float f) {
    __hip_bfloat16 h = __float2bfloat16(f);
    return *reinterpret_cast<unsigned short*>(&h);
}
__device__ __forceinline__ void gload16(const void* g, void* l) {
    __builtin_amdgcn_global_load_lds(
        (__attribute__((address_space(1))) void*)g,
        (__attribute__((address_space(3))) void*)l, 16, 0, 0);
}

// Swizzled granule layout (16B granules): stored_chunk = chunk ^ (row & 7).
// Staging lane-linear dest + permuted source = coalesced; frag ds_read_b128
// spreads 16 lanes over 8 bank-quads (2-way = free).

// ---------------------------------------------------------------------------
// prep: Wcat (NPAD x 256 bf16), Wo (256x256 bf16), bcat (fp32 NPAD)
// ---------------------------------------------------------------------------
__global__ __launch_bounds__(256) void prep_weights(
    const float* __restrict__ vw, const float* __restrict__ vb,
    const float* __restrict__ ow, const float* __restrict__ ob,
    const float* __restrict__ aw, const float* __restrict__ ab,
    const float* __restrict__ outw,
    unsigned short* __restrict__ Wcat, unsigned short* __restrict__ Wo,
    float* __restrict__ bcat)
{
    int i = blockIdx.x * 256 + threadIdx.x;
    if (i < NPAD * E) {
        int n = i >> 8, k = i & 255;
        float w = 0.f;
        if      (n < 256) w = vw[n * E + k];
        else if (n < 320) w = ow[(n - 256) * E + k];
        else if (n < 352) w = aw[(n - 320) * E + k];
        Wcat[i] = f2b(w);
    } else {
        int j = i - NPAD * E;
        if (j < E * E) Wo[j] = f2b(outw[j]);
    }
    if (i < NPAD) {
        float bv = 0.f;
        if      (i < 256) bv = vb[i];
        else if (i < 320) bv = ob[i - 256];
        else if (i < 352) bv = ab[i - 320];
        bcat[i] = bv;
    }
}

// ---------------------------------------------------------------------------
// GEMM1 (projection): 64 rows x 384 cols per block -> query read ONCE.
// BK=64, 4 K-steps. 8 waves (2m x 4n), wave tile 32x96. LDS 56KB.
// ---------------------------------------------------------------------------
__global__ __launch_bounds__(512) void gemm_proj(
    const float* __restrict__ Aq,
    const unsigned short* __restrict__ W,
    const float* __restrict__ bias,
    unsigned short* __restrict__ Vt,
    unsigned short* __restrict__ Mt)
{
    __shared__ __align__(16) unsigned short ldsA[4096];   // 512 granules
    __shared__ __align__(16) unsigned short ldsB[24576];  // 3072 granules

    const int tid  = threadIdx.x;
    const int lane = tid & 63;
    const int wave = tid >> 6;      // 0..7
    const int wm   = wave >> 2;     // 0..1 : 32-row halves
    const int wn   = wave & 3;      // 0..3 : 96-col quarters
    const int bm   = blockIdx.x * 64;
    const int lrow = lane & 15, lchunk = lane >> 4;

    f32x4 acc[2][6] = {};

    for (int k0 = 0; k0 < 256; k0 += 64) {
#pragma unroll
        for (int p = 0; p < 6; ++p) {
            int g = p * 512 + tid;
            int row = g >> 3;
            int c = (g & 7) ^ (row & 7);
            gload16(W + (size_t)row * 256 + k0 + c * 8, &ldsB[(size_t)g * 8]);
        }
        {
            int row = tid >> 3;
            int c = (tid & 7) ^ (row & 7);
            const float* ap = Aq + (size_t)(bm + row) * 256 + k0 + c * 8;
            float4 f0 = *(const float4*)(ap + 0);
            float4 f1 = *(const float4*)(ap + 4);
            u16x8 o;
            o[0]=f2b(f0.x); o[1]=f2b(f0.y); o[2]=f2b(f0.z); o[3]=f2b(f0.w);
            o[4]=f2b(f1.x); o[5]=f2b(f1.y); o[6]=f2b(f1.z); o[7]=f2b(f1.w);
            *(u16x8*)&ldsA[(size_t)tid * 8] = o;
        }
        __syncthreads();

#pragma unroll
        for (int kk = 0; kk < 2; ++kk) {
            const int C = kk * 4 + lchunk;
            bf16x8 af[2], bfr[6];
#pragma unroll
            for (int m = 0; m < 2; ++m) {
                int row = wm * 32 + m * 16 + lrow;
                af[m] = *(const bf16x8*)&ldsA[(size_t)(row * 8 + (C ^ (row & 7))) * 8];
            }
#pragma unroll
            for (int n = 0; n < 6; ++n) {
                int row = wn * 96 + n * 16 + lrow;
                bfr[n] = *(const bf16x8*)&ldsB[(size_t)(row * 8 + (C ^ (row & 7))) * 8];
            }
#pragma unroll
            for (int m = 0; m < 2; ++m)
#pragma unroll
                for (int n = 0; n < 6; ++n)
                    acc[m][n] = __builtin_amdgcn_mfma_f32_16x16x32_bf16(
                        af[m], bfr[n], acc[m][n], 0, 0, 0);
        }
        __syncthreads();
    }

    const int orow0 = (lane >> 4) * 4;
    const int ocol  = lane & 15;
#pragma unroll
    for (int n = 0; n < 6; ++n) {
        int colg = wn * 96 + n * 16 + ocol;
        if (colg >= 352) continue;
        float bv = bias[colg];
#pragma unroll
        for (int m = 0; m < 2; ++m) {
#pragma unroll
            for (int r = 0; r < 4; ++r) {
                int rowg = bm + wm * 32 + m * 16 + orow0 + r;
                unsigned short v = f2b(acc[m][n][r] + bv);
                if (colg < 256) {
                    int b = rowg >> 12, q = rowg & 4095;
                    int h = colg >> 5, ch = colg & 31;
                    Vt[((size_t)(((b << 3) + h) << 12) + q) * 32 + ch] = v;
                } else if (colg < 320) {
                    int idx = colg - 256;           // 0..63 : offsets
                    Mt[(size_t)rowg * MSTR + (idx >> 3) * 16 + (idx & 7)] = v;
                } else {
                    int idx = colg - 320;           // 0..31 : logits
                    Mt[(size_t)rowg * MSTR + (idx >> 2) * 16 + 8 + (idx & 3)] = v;
                }
            }
        }
    }
}

// ---------------------------------------------------------------------------
// Sampling: thread per (t, h, 8-ch group); 4096 blocks, XCD-swizzled so each
// XCD's L2 holds one batch image (2 MB). Branchless clamped+masked bilinear.
// Meta for (t,h) is one 24B packed segment -> single-line meta reads.
// (structure identical to round 8 — proven latency-optimal mapping)
// ---------------------------------------------------------------------------
__global__ __launch_bounds__(256) void sample_kernel(
    const unsigned short* __restrict__ Vt,
    const unsigned short* __restrict__ Mt,
    unsigned short* __restrict__ S)
{
    const int blk = ((blockIdx.x & 7) << 9) + (blockIdx.x >> 3);  // 4096 = 8*512
    const int gid = blk * 256 + threadIdx.x;
    const int d0 = gid & 3;
    const int h  = (gid >> 2) & 7;
    const int t  = gid >> 5;
    const int b  = t >> 12;
    const int q  = t & 4095;

    const float refx = (float)(q & 63) * (64.0f / 63.0f);
    const float refy = (float)(q >> 6) * (64.0f / 63.0f);

    const unsigned short* __restrict__ mrow = Mt + (size_t)t * MSTR + h * 16;
    u16x8  offv = *(const u16x8*)&mrow[0];
    ushort4 lg  = *(const ushort4*)&mrow[8];

    float l0 = b2f(lg.x), l1 = b2f(lg.y), l2 = b2f(lg.z), l3 = b2f(lg.w);
    float m = fmaxf(fmaxf(l0, l1), fmaxf(l2, l3));
    float e0 = __expf(l0 - m), e1 = __expf(l1 - m);
    float e2 = __expf(l2 - m), e3 = __expf(l3 - m);
    float inv = 1.0f / (e0 + e1 + e2 + e3);
    float at[4] = {e0 * inv, e1 * inv, e2 * inv, e3 * inv};

    const unsigned short* __restrict__ vbase =
        Vt + ((size_t)(((b << 3) + h) << 12)) * 32 + d0 * 8;

    float acc[8] = {};
#pragma unroll
    for (int p = 0; p < NP; ++p) {
        float ox = b2f(offv[2 * p]);
        float oy = b2f(offv[2 * p + 1]);
        float px = refx + ox - 0.5f;
        float py = refy + oy - 0.5f;
        float fx = floorf(px), fy = floorf(py);
        int x0 = (int)fx, y0 = (int)fy;
        float wx = px - fx, wy = py - fy;
        float a = at[p];

        int x1 = x0 + 1, y1 = y0 + 1;
        float vx0 = (x0 >= 0 && x0 < GW) ? 1.f : 0.f;
        float vx1 = (x1 >= 0 && x1 < GW) ? 1.f : 0.f;
        float vy0 = (y0 >= 0 && y0 < GH) ? 1.f : 0.f;
        float vy1 = (y1 >= 0 && y1 < GH) ? 1.f : 0.f;

        float w00 = (1.f - wx) * (1.f - wy) * a * vx0 * vy0;
        float w10 = wx * (1.f - wy) * a * vx1 * vy0;
        float w01 = (1.f - wx) * wy * a * vx0 * vy1;
        float w11 = wx * wy * a * vx1 * vy1;

        int x0c = min(max(x0, 0), GW - 1), x1c = min(max(x1, 0), GW - 1);
        int y0c = min(max(y0, 0), GH - 1), y1c = min(max(y1, 0), GH - 1);

        u16x8 g00 = *(const u16x8*)&vbase[(size_t)(y0c * GW + x0c) * 32];
        u16x8 g10 = *(const u16x8*)&vbase[(size_t)(y0c * GW + x1c) * 32];
        u16x8 g01 = *(const u16x8*)&vbase[(size_t)(y1c * GW + x0c) * 32];
        u16x8 g11 = *(const u16x8*)&vbase[(size_t)(y1c * GW + x1c) * 32];
#pragma unroll
        for (int j = 0; j < 8; ++j)
            acc[j] += w00 * b2f(g00[j]) + w10 * b2f(g10[j])
                    + w01 * b2f(g01[j]) + w11 * b2f(g11[j]);
    }

    u16x8 o;
#pragma unroll
    for (int j = 0; j < 8; ++j) o[j] = f2b(acc[j]);
    *(u16x8*)&S[(size_t)t * E + h * HD + d0 * 8] = o;
}

// ---------------------------------------------------------------------------
// GEMM2 (output projection): 64 rows x 256 cols per block -> S read ONCE.
// BK=64, 4 K-steps. 8 waves (2m x 4n), wave tile 32x64. LDS 40KB.
// ---------------------------------------------------------------------------
__global__ __launch_bounds__(512) void gemm_out(
    const unsigned short* __restrict__ A,
    const unsigned short* __restrict__ W,
    const float* __restrict__ bias,
    const float* __restrict__ resid,
    float* __restrict__ Out)
{
    __shared__ __align__(16) unsigned short ldsA[4096];   // 512 granules
    __shared__ __align__(16) unsigned short ldsB[16384];  // 2048 granules

    const int tid  = threadIdx.x;
    const int lane = tid & 63;
    const int wave = tid >> 6;
    const int wm   = wave >> 2;
    const int wn   = wave & 3;
    const int bm   = blockIdx.x * 64;
    const int lrow = lane & 15, lchunk = lane >> 4;

    f32x4 acc[2][4] = {};

    for (int k0 = 0; k0 < 256; k0 += 64) {
        {
            int row = tid >> 3;
            int c = (tid & 7) ^ (row & 7);
            gload16(A + (size_t)(bm + row) * 256 + k0 + c * 8,
                    &ldsA[(size_t)tid * 8]);
        }
#pragma unroll
        for (int p = 0; p < 4; ++p) {
            int g = p * 512 + tid;
            int row = g >> 3;
            int c = (g & 7) ^ (row & 7);
            gload16(W + (size_t)row * 256 + k0 + c * 8, &ldsB[(size_t)g * 8]);
        }
        __syncthreads();

#pragma unroll
        for (int kk = 0; kk < 2; ++kk) {
            const int C = kk * 4 + lchunk;
            bf16x8 af[2], bfr[4];
#pragma unroll
            for (int m = 0; m < 2; ++m) {
                int row = wm * 32 + m * 16 + lrow;
                af[m] = *(const bf16x8*)&ldsA[(size_t)(row * 8 + (C ^ (row & 7))) * 8];
            }
#pragma unroll
            for (int n = 0; n < 4; ++n) {
                int row = wn * 64 + n * 16 + lrow;
                bfr[n] = *(const bf16x8*)&ldsB[(size_t)(row * 8 + (C ^ (row & 7))) * 8];
            }
#pragma unroll
            for (int m = 0; m < 2; ++m)
#pragma unroll
                for (int n = 0; n < 4; ++n)
                    acc[m][n] = __builtin_amdgcn_mfma_f32_16x16x32_bf16(
                        af[m], bfr[n], acc[m][n], 0, 0, 0);
        }
        __syncthreads();
    }

    const int orow0 = (lane >> 4) * 4;
    const int ocol  = lane & 15;
#pragma unroll
    for (int m = 0; m < 2; ++m) {
#pragma unroll
        for (int n = 0; n < 4; ++n) {
            int colg = wn * 64 + n * 16 + ocol;
            float bv = bias[colg];
#pragma unroll
            for (int r = 0; r < 4; ++r) {
                int rowg = bm + wm * 32 + m * 16 + orow0 + r;
                Out[(size_t)rowg * 256 + colg] =
                    acc[m][n][r] + bv + 2.0f * resid[(size_t)rowg * 256 + colg];
            }
        }
    }
}

// ---------------------------------------------------------------------------
extern "C" void kernel_launch(void* const* d_in, const int* in_sizes, int n_in,
                              void* d_out, int out_size, void* d_ws, size_t ws_size,
                              hipStream_t stream)
{
    const float* query   = (const float*)d_in[0];
    const float* value_w = (const float*)d_in[1];
    const float* value_b = (const float*)d_in[2];
    const float* off_w   = (const float*)d_in[3];
    const float* off_b   = (const float*)d_in[4];
    const float* attn_w  = (const float*)d_in[5];
    const float* attn_b  = (const float*)d_in[6];
    const float* out_w   = (const float*)d_in[7];
    const float* out_b   = (const float*)d_in[8];

    char* w = (char*)d_ws;
    unsigned short* Vt   = (unsigned short*)w;  w += (size_t)T * E * 2;      // 16 MB
    unsigned short* Mt   = (unsigned short*)w;  w += (size_t)T * MSTR * 2;   // 8 MB
    unsigned short* S    = (unsigned short*)w;  w += (size_t)T * E * 2;      // 16 MB
    unsigned short* Wcat = (unsigned short*)w;  w += (size_t)NPAD * E * 2;
    unsigned short* Wo   = (unsigned short*)w;  w += (size_t)E * E * 2;
    float*          bcat = (float*)w;

    prep_weights<<<(NPAD * E + E * E + 255) / 256, 256, 0, stream>>>(
        value_w, value_b, off_w, off_b, attn_w, attn_b, out_w, Wcat, Wo, bcat);

    gemm_proj<<<T / 64, 512, 0, stream>>>(query, Wcat, bcat, Vt, Mt);

    sample_kernel<<<T * 32 / 256, 256, 0, stream>>>(Vt, Mt, S);

    gemm_out<<<T / 64, 512, 0, stream>>>(S, Wo, out_b, query, (float*)d_out);
}